// Round 11
// baseline (104.988 us; speedup 1.0000x reference)
//
#include <hip/hip_runtime.h>
#include <math.h>

#define Bn 32
#define Qn 300
#define Tn 64
#define Cn 2
#define Mcols Qn   /* LSA columns (queries) */
#define Nrows Tn   /* LSA rows (targets)   */
#define NSLOT 5    /* ceil(300/64) columns per lane */

#define CLS_SCALE_F 0.1f
#define BBOX_SCALE_D 5.0
#define GIOU_SCALE_D 2.0

typedef unsigned int uint2v __attribute__((ext_vector_type(2)));

// ---------------------------------------------------------------------------
// Lexicographic (value, pack) min reduction stages (rounds 5/8/9/10-proven).
// ---------------------------------------------------------------------------
template <int CTRL>
__device__ __forceinline__ void lexmin_dpp(double& bv, int& bp) {
    int lo = __builtin_amdgcn_update_dpp(0, __double2loint(bv), CTRL, 0xF, 0xF, true);
    int hi = __builtin_amdgcn_update_dpp(0, __double2hiint(bv), CTRL, 0xF, 0xF, true);
    int op = __builtin_amdgcn_update_dpp(0, bp,                 CTRL, 0xF, 0xF, true);
    double ov = __hiloint2double(hi, lo);
    if (ov < bv || (ov == bv && op < bp)) { bv = ov; bp = op; }
}
__device__ __forceinline__ void lexmin_shfl(double& bv, int& bp, int off) {
    double ov = __shfl_xor(bv, off);
    int    op = __shfl_xor(bp, off);
    if (ov < bv || (ov == bv && op < bp)) { bv = ov; bp = op; }
}
#if __has_builtin(__builtin_amdgcn_permlane16_swap) && __has_builtin(__builtin_amdgcn_permlane32_swap)
__device__ __forceinline__ void lexmin_pl16(double& bv, int& bp) {
    uint2v rlo = __builtin_amdgcn_permlane16_swap((unsigned)__double2loint(bv), (unsigned)__double2loint(bv), false, false);
    uint2v rhi = __builtin_amdgcn_permlane16_swap((unsigned)__double2hiint(bv), (unsigned)__double2hiint(bv), false, false);
    uint2v rpk = __builtin_amdgcn_permlane16_swap((unsigned)bp, (unsigned)bp, false, false);
    double av = __hiloint2double((int)rhi[0], (int)rlo[0]); int ap = (int)rpk[0];
    double bw = __hiloint2double((int)rhi[1], (int)rlo[1]); int bq = (int)rpk[1];
    if (av < bw || (av == bw && ap < bq)) { bv = av; bp = ap; } else { bv = bw; bp = bq; }
}
__device__ __forceinline__ void lexmin_pl32(double& bv, int& bp) {
    uint2v rlo = __builtin_amdgcn_permlane32_swap((unsigned)__double2loint(bv), (unsigned)__double2loint(bv), false, false);
    uint2v rhi = __builtin_amdgcn_permlane32_swap((unsigned)__double2hiint(bv), (unsigned)__double2hiint(bv), false, false);
    uint2v rpk = __builtin_amdgcn_permlane32_swap((unsigned)bp, (unsigned)bp, false, false);
    double av = __hiloint2double((int)rhi[0], (int)rlo[0]); int ap = (int)rpk[0];
    double bw = __hiloint2double((int)rhi[1], (int)rlo[1]); int bq = (int)rpk[1];
    if (av < bw || (av == bw && ap < bq)) { bv = av; bp = ap; } else { bv = bw; bp = bq; }
}
#else
__device__ __forceinline__ void lexmin_pl16(double& bv, int& bp) { lexmin_shfl(bv, bp, 16); }
__device__ __forceinline__ void lexmin_pl32(double& bv, int& bp) { lexmin_shfl(bv, bp, 32); }
#endif

// ---------------------------------------------------------------------------
// Cost kernel (massively parallel): cost[b][t][q] = L1 - p_class - giou (f32)
// ---------------------------------------------------------------------------
__global__ __launch_bounds__(256) void cost_kernel(
    const float* __restrict__ logits,        // [B][Q][C]
    const float* __restrict__ pred_bbox,     // [B][Q][4]
    const float* __restrict__ target_bbox,   // [B][T][4]
    const int*   __restrict__ target_labels, // [B][T]
    float* __restrict__ cost)                // [B][T][Q]
{
    int idx = blockIdx.x * blockDim.x + threadIdx.x;
    const int total = Bn * Nrows * Mcols;
    if (idx >= total) return;
    int q = idx % Mcols;
    int t = (idx / Mcols) % Nrows;
    int b = idx / (Mcols * Nrows);

    float l0 = logits[(b * Qn + q) * Cn + 0];
    float l1 = logits[(b * Qn + q) * Cn + 1];
    float mx = fmaxf(l0, l1);
    float e0 = expf(l0 - mx), e1 = expf(l1 - mx);
    float den = e0 + e1;
    float pce0 = e0 / den, pce1 = e1 / den;
    float cost_class = (target_labels[b * Tn + t] == 0) ? -pce0 : -pce1;

    const float* pb = pred_bbox + (b * Qn + q) * 4;
    const float* tb = target_bbox + (b * Tn + t) * 4;
    float pcx = pb[0], pcy = pb[1], pw = pb[2], ph = pb[3];
    float tcx = tb[0], tcy = tb[1], tw = tb[2], th = tb[3];
    float cost_bbox = fabsf(pcx - tcx) + fabsf(pcy - tcy) +
                      fabsf(pw - tw) + fabsf(ph - th);

    float p0 = pcx - 0.5f * pw, p1 = pcy - 0.5f * ph;
    float p2 = pcx + 0.5f * pw, p3 = pcy + 0.5f * ph;
    float t0 = tcx - 0.5f * tw, t1 = tcy - 0.5f * th;
    float t2 = tcx + 0.5f * tw, t3 = tcy + 0.5f * th;
    float area1 = (p2 - p0) * (p3 - p1);
    float area2 = (t2 - t0) * (t3 - t1);
    float ltx = fmaxf(p0, t0), lty = fmaxf(p1, t1);
    float rbx = fminf(p2, t2), rby = fminf(p3, t3);
    float iw = fmaxf(rbx - ltx, 0.0f), ih = fmaxf(rby - lty, 0.0f);
    float inter = iw * ih;
    float uni   = area1 + area2 - inter;
    float iou   = inter / uni;
    float ex0 = fminf(p0, t0), ey0 = fminf(p1, t1);
    float ex1 = fmaxf(p2, t2), ey1 = fmaxf(p3, t3);
    float ew = fmaxf(ex1 - ex0, 0.0f), eh = fmaxf(ey1 - ey0, 0.0f);
    float enc = ew * eh;
    float giou = iou - (enc - uni) / enc;

    cost[((size_t)b * Nrows + t) * Mcols + q] = cost_bbox + cost_class - giou;
}

// ---------------------------------------------------------------------------
// LSA kernel: stage (or build) 64x300 cost tile in LDS, then:
// Phase 0 — row-reduction warm start (u[i]=rowmin, greedy assign if argmin
//   column free). PIPELINED: next row's costs prefetched under the current
//   reduce; argmin via the proven f64 lexmin stack (uniform jstar, no shfl);
//   occupancy check via per-lane colTaken bitmask + ballot (no LDS read);
//   p_lds writes fire-and-forget, fenced once before Phase 1.
// Phase 1 — rounds-9/10-proven JV Dijkstra for deferred rows with feasible
//   warm duals (c-u-v >= 0, matched edges tight) => optimal assignment =
//   reference's (unique optimum; validated absmax 0.0 in round 10).
// ---------------------------------------------------------------------------
__global__ __launch_bounds__(64) void lsa_kernel(
    const float* __restrict__ logits,
    const float* __restrict__ pred_bbox,
    const float* __restrict__ target_bbox,
    const int*   __restrict__ target_labels,
    const float* __restrict__ gcost,   // [B][T][Q] or unused
    int use_gcost,
    int* __restrict__ src)             // [B][T] -> matched query
{
    const int b   = blockIdx.x;
    const int tid = threadIdx.x;

    __shared__ float cst[Nrows * Mcols];   // 76800 B
    __shared__ int   p_lds[Mcols + 1];
    __shared__ int   way_lds[Mcols + 1];
    __shared__ float tb4[Tn * 4];
    __shared__ int   tlab[Tn];

    for (int j = tid; j <= Mcols; j += 64) { p_lds[j] = 0; way_lds[j] = 0; }
    src[b * Tn + tid] = tid;   // identity fallback; overwritten by emit

    if (use_gcost) {
        const float* gb = gcost + (size_t)b * Nrows * Mcols;
        for (int k = 0; k < 75; ++k) {
            __builtin_amdgcn_global_load_lds(
                (const __attribute__((address_space(1))) void*)(gb + k * 256 + tid * 4),
                (__attribute__((address_space(3))) void*)(cst + k * 256),
                16, 0, 0);
        }
    } else {
        for (int k = tid; k < Tn * 4; k += 64) tb4[k] = target_bbox[b * Tn * 4 + k];
        for (int k = tid; k < Tn; k += 64)     tlab[k] = target_labels[b * Tn + k];
        __syncthreads();
        for (int qt = 0; qt < NSLOT; ++qt) {
            int q = qt * 64 + tid;
            if (q < Qn) {
                float l0 = logits[(b * Qn + q) * Cn + 0];
                float l1 = logits[(b * Qn + q) * Cn + 1];
                float mx = fmaxf(l0, l1);
                float e0 = expf(l0 - mx), e1 = expf(l1 - mx);
                float den = e0 + e1;
                float pce0 = e0 / den, pce1 = e1 / den;

                const float* pb = pred_bbox + (b * Qn + q) * 4;
                float pcx = pb[0], pcy = pb[1], pw = pb[2], ph = pb[3];
                float p0 = pcx - 0.5f * pw, p1 = pcy - 0.5f * ph;
                float p2 = pcx + 0.5f * pw, p3 = pcy + 0.5f * ph;
                float area1 = (p2 - p0) * (p3 - p1);

                for (int t = 0; t < Tn; ++t) {
                    float tcx = tb4[t * 4 + 0], tcy = tb4[t * 4 + 1];
                    float tw  = tb4[t * 4 + 2], th  = tb4[t * 4 + 3];
                    float cost_bbox = fabsf(pcx - tcx) + fabsf(pcy - tcy) +
                                      fabsf(pw - tw) + fabsf(ph - th);
                    float cost_class = (tlab[t] == 0) ? -pce0 : -pce1;

                    float t0 = tcx - 0.5f * tw, t1 = tcy - 0.5f * th;
                    float t2 = tcx + 0.5f * tw, t3 = tcy + 0.5f * th;
                    float area2 = (t2 - t0) * (t3 - t1);
                    float ltx = fmaxf(p0, t0), lty = fmaxf(p1, t1);
                    float rbx = fminf(p2, t2), rby = fminf(p3, t3);
                    float iw = fmaxf(rbx - ltx, 0.0f), ih = fmaxf(rby - lty, 0.0f);
                    float inter = iw * ih;
                    float uni   = area1 + area2 - inter;
                    float iou   = inter / uni;
                    float ex0 = fminf(p0, t0), ey0 = fminf(p1, t1);
                    float ex1 = fmaxf(p2, t2), ey1 = fmaxf(p3, t3);
                    float ew = fmaxf(ex1 - ex0, 0.0f), eh = fmaxf(ey1 - ey0, 0.0f);
                    float enc = ew * eh;
                    float giou = iou - (enc - uni) / enc;

                    cst[t * Mcols + q] = cost_bbox + cost_class - giou;
                }
            }
        }
    }
    __syncthreads();   // tile + bookkeeping visible (drains vmcnt for DMA)

    // ---- registerized hot state: lane owns columns j-1 = s*64 + tid ----
    double v_[NSLOT], minv_[NSLOT];
    int    pcs_[NSLOT];
    double u_ = 0.0;
    unsigned usedM;
    #pragma unroll
    for (int s = 0; s < NSLOT; ++s) v_[s] = 0.0;

    const bool valid_[NSLOT] = {
        true, true, true, true, (4 * 64 + tid) < Mcols
    };

    // ---- Phase 0: pipelined row-reduction warm start ----
    unsigned long long matchedRows = 0ULL;
    unsigned colTaken = 0u;   // bit s: column s*64+tid taken (this lane owns)
    float c5cur[NSLOT], c5nxt[NSLOT];
    #pragma unroll
    for (int s = 0; s < NSLOT; ++s) {
        int jj = s * 64 + tid; if (jj >= Mcols) jj = 0;
        c5cur[s] = cst[jj];                       // row 1 (index 0)
    }
    for (int i = 1; i <= Nrows; ++i) {
        if (i < Nrows) {
            #pragma unroll
            for (int s = 0; s < NSLOT; ++s) {     // prefetch row i+1 (index i)
                int jj = s * 64 + tid; if (jj >= Mcols) jj = 0;
                c5nxt[s] = cst[i * Mcols + jj];
            }
        }
        // lane-local lex argmin over (cost, j); s ascending => first index
        double bestv = INFINITY; int bestpack = 0x7fffffff;
        #pragma unroll
        for (int s = 0; s < NSLOT; ++s) {
            if (valid_[s]) {
                int j = s * 64 + tid + 1;
                double c = (double)c5cur[s];
                if (c < bestv) { bestv = c; bestpack = (j << 8); }
            }
        }
        lexmin_dpp<0xB1>(bestv, bestpack);    // quad_perm xor1
        lexmin_dpp<0x4E>(bestv, bestpack);    // quad_perm xor2
        lexmin_dpp<0x124>(bestv, bestpack);   // row_ror:4
        lexmin_dpp<0x128>(bestv, bestpack);   // row_ror:8
        lexmin_pl16(bestv, bestpack);         // 16-lane row swap
        lexmin_pl32(bestv, bestpack);         // 32-lane half swap
        int jstar = bestpack >> 8;            // uniform across lanes

        int slot = (jstar - 1) >> 6, lane = (jstar - 1) & 63;
        bool takenMine = (lane == tid) && ((colTaken >> slot) & 1u);
        bool occupied = (__ballot(takenMine) != 0ULL);
        if (!occupied) {
            if (lane == tid) colTaken |= (1u << slot);
            if (tid == 0) p_lds[jstar] = i;   // fire-and-forget (fenced below)
            matchedRows |= (1ULL << (i - 1));
        }
        if (tid == i - 1) u_ = bestv;         // u[i] = rowmin (exact)

        if (i < Nrows) {
            #pragma unroll
            for (int s = 0; s < NSLOT; ++s) c5cur[s] = c5nxt[s];
        }
    }
    __syncthreads();   // p_lds writes visible before Phase-1 snapshots

    // ---- Phase 1: JV Dijkstra for deferred rows (rounds 9/10-proven) ----
    for (int i = 1; i <= Nrows; ++i) {
        if ((matchedRows >> (i - 1)) & 1ULL) continue;

        #pragma unroll
        for (int s = 0; s < NSLOT; ++s) {
            int j = s * 64 + tid + 1;
            pcs_[s] = valid_[s] ? p_lds[j] : 0;
            minv_[s] = INFINITY;
        }
        usedM = 0;
        bool inTree = (tid == i - 1);   // row i is the tree root
        int j0cur = 0;
        int j1 = 0, pj1 = 0;

        // preload row i costs + u[i]
        double ui0 = __shfl(u_, i - 1);
        float c5[NSLOT];
        #pragma unroll
        for (int s = 0; s < NSLOT; ++s) {
            int jj = s * 64 + tid; if (jj >= Mcols) jj = 0;
            c5[s] = cst[(i - 1) * Mcols + jj];
        }

        for (int step = 0; step <= Mcols + 1; ++step) {
            // relax free columns; lane-local lex argmin (s asc => j asc)
            double bestv = INFINITY;
            int bestpack = 0x7fffffff;   // (j<<8)|p[j]
            #pragma unroll
            for (int s = 0; s < NSLOT; ++s) {
                if (valid_[s] && !((usedM >> s) & 1u)) {
                    int j = s * 64 + tid + 1;
                    double cur = ((double)c5[s] - ui0) - v_[s];
                    if (cur < minv_[s]) { minv_[s] = cur; way_lds[j] = j0cur; }
                    if (minv_[s] < bestv) {
                        bestv = minv_[s];
                        bestpack = (j << 8) | pcs_[s];
                    }
                }
            }
            // wave-wide lex (value, j) argmin (proven stages)
            lexmin_dpp<0xB1>(bestv, bestpack);    // quad_perm xor1
            lexmin_dpp<0x4E>(bestv, bestpack);    // quad_perm xor2
            lexmin_dpp<0x124>(bestv, bestpack);   // row_ror:4
            lexmin_dpp<0x128>(bestv, bestpack);   // row_ror:8
            lexmin_pl16(bestv, bestpack);         // 16-lane row swap
            lexmin_pl32(bestv, bestpack);         // 32-lane half swap

            double delta = bestv;
            j1  = bestpack >> 8;
            pj1 = bestpack & 0xff;

            bool brk = (pj1 == 0);
            if (!brk) {
                // prefetch next row's u and costs; latency overlaps dual update
                ui0 = __shfl(u_, pj1 - 1);
                #pragma unroll
                for (int s = 0; s < NSLOT; ++s) {
                    int jj = s * 64 + tid; if (jj >= Mcols) jj = 0;
                    c5[s] = cst[(pj1 - 1) * Mcols + jj];
                }
            }

            // dual update (reference order; usedM excludes j1 this step)
            if (inTree) u_ += delta;
            #pragma unroll
            for (int s = 0; s < NSLOT; ++s) {
                if ((usedM >> s) & 1u) v_[s] -= delta;
                else if (valid_[s])    minv_[s] -= delta;
            }

            if (brk) break;

            if (((j1 - 1) & 63) == tid) usedM |= 1u << ((j1 - 1) >> 6);
            if (tid == pj1 - 1) inTree = true;
            j0cur = j1;
        }

        __syncthreads();   // way_lds stores visible before augment
        if (tid == 0) {
            int jj = j1;
            for (int st = 0; st < Mcols + 2 && jj != 0; ++st) {
                int jn = way_lds[jj];
                p_lds[jj] = (jn == 0) ? i : p_lds[jn];
                jj = jn;
            }
        }
        __syncthreads();   // p_lds updated before next snapshot
    }

    // ---- emit assignment (guarded) ----
    for (int j = tid + 1; j <= Mcols; j += 64) {
        int pi = p_lds[j];
        if (pi > 0 && pi <= Nrows) src[b * Tn + (pi - 1)] = j - 1;
    }
}

// ---------------------------------------------------------------------------
// Loss kernel: per-batch partials. Deterministic tree reduce, doubles.
// ---------------------------------------------------------------------------
__global__ __launch_bounds__(256) void loss_kernel(
    const float* __restrict__ logits,
    const float* __restrict__ pred_bbox,
    const float* __restrict__ target_bbox,
    const int*   __restrict__ target_labels,
    const int*   __restrict__ src,
    double* __restrict__ partials)
{
    const int b = blockIdx.x;
    const int tid = threadIdx.x;
    __shared__ int cls[Qn];
    for (int q = tid; q < Qn; q += 256) cls[q] = Cn - 1;
    __syncthreads();
    if (tid < Tn) {
        unsigned q = (unsigned)src[b * Tn + tid];
        if (q >= Qn) q = 0;
        cls[q] = target_labels[b * Tn + tid];
    }
    __syncthreads();

    double s_wnll = 0.0, s_w = 0.0, s_l1 = 0.0, s_giou = 0.0;

    for (int q = tid; q < Qn; q += 256) {
        float l0 = logits[(b * Qn + q) * Cn + 0];
        float l1 = logits[(b * Qn + q) * Cn + 1];
        float mx = fmaxf(l0, l1);
        float lse = mx + logf(expf(l0 - mx) + expf(l1 - mx));
        int tc = cls[q];
        float lt = (tc == 0) ? l0 : l1;
        float nll = lse - lt;
        float wt = (tc == Cn - 1) ? CLS_SCALE_F : 1.0f;
        s_wnll += (double)(wt * nll);
        s_w    += (double)wt;
    }

    if (tid < Tn) {
        int t = tid;
        unsigned q = (unsigned)src[b * Tn + t];
        if (q >= Qn) q = 0;
        const float* pb = pred_bbox + ((size_t)b * Qn + q) * 4;
        const float* tb = target_bbox + ((size_t)b * Tn + t) * 4;
        float pcx = pb[0], pcy = pb[1], pw = pb[2], ph = pb[3];
        float tcx = tb[0], tcy = tb[1], tw = tb[2], th = tb[3];
        s_l1 = (double)(fabsf(pcx - tcx) + fabsf(pcy - tcy) +
                        fabsf(pw - tw) + fabsf(ph - th));

        float p0 = pcx - 0.5f * pw, p1 = pcy - 0.5f * ph;
        float p2 = pcx + 0.5f * pw, p3 = pcy + 0.5f * ph;
        float t0 = tcx - 0.5f * tw, t1 = tcy - 0.5f * th;
        float t2 = tcx + 0.5f * tw, t3 = tcy + 0.5f * th;
        float area1 = (p2 - p0) * (p3 - p1);
        float area2 = (t2 - t0) * (t3 - t1);
        float ltx = fmaxf(p0, t0), lty = fmaxf(p1, t1);
        float rbx = fminf(p2, t2), rby = fminf(p3, t3);
        float iw = fmaxf(rbx - ltx, 0.0f), ih = fmaxf(rby - lty, 0.0f);
        float inter = iw * ih;
        float uni = area1 + area2 - inter;
        float iou = inter / uni;
        float ex0 = fminf(p0, t0), ey0 = fminf(p1, t1);
        float ex1 = fmaxf(p2, t2), ey1 = fmaxf(p3, t3);
        float ew = fmaxf(ex1 - ex0, 0.0f), eh = fmaxf(ey1 - ey0, 0.0f);
        float enc = ew * eh;
        float giou = iou - (enc - uni) / enc;
        s_giou = (double)(1.0f - giou);
    }

    __shared__ double rbuf[256];
    double vals[4] = { s_wnll, s_w, s_l1, s_giou };
    for (int k = 0; k < 4; ++k) {
        rbuf[tid] = vals[k];
        __syncthreads();
        for (int s = 128; s > 0; s >>= 1) {
            if (tid < s) rbuf[tid] += rbuf[tid + s];
            __syncthreads();
        }
        if (tid == 0) partials[b * 4 + k] = rbuf[0];
        __syncthreads();
    }
}

// ---------------------------------------------------------------------------
__global__ void finalize_kernel(const double* __restrict__ partials,
                                float* __restrict__ out)
{
    if (threadIdx.x != 0 || blockIdx.x != 0) return;
    double wnll = 0.0, w = 0.0, l1 = 0.0, gi = 0.0;
    for (int b = 0; b < Bn; ++b) {
        wnll += partials[b * 4 + 0];
        w    += partials[b * 4 + 1];
        l1   += partials[b * 4 + 2];
        gi   += partials[b * 4 + 3];
    }
    double nb = (double)(Bn * Tn);
    double loss = wnll / w + BBOX_SCALE_D * (l1 / nb) + GIOU_SCALE_D * (gi / nb);
    out[0] = (float)loss;
}

// ---------------------------------------------------------------------------
extern "C" void kernel_launch(void* const* d_in, const int* in_sizes, int n_in,
                              void* d_out, int out_size, void* d_ws, size_t ws_size,
                              hipStream_t stream)
{
    const float* logits        = (const float*)d_in[0];
    const float* pred_bbox     = (const float*)d_in[1];
    const float* target_bbox   = (const float*)d_in[2];
    const int*   target_labels = (const int*)d_in[3];
    float* out = (float*)d_out;

    char* ws = (char*)d_ws;
    int* src = (int*)ws;                                   // 8192 B
    double* partials = (double*)(ws + 8448);               // 1024 B
    float* gcost = (float*)(ws + 16384);                   // 2457600 B (optional)

    const size_t cost_bytes = (size_t)Bn * Nrows * Mcols * sizeof(float);
    const int use_gcost = (ws_size >= 16384 + cost_bytes) ? 1 : 0;

    if (use_gcost) {
        const int total = Bn * Nrows * Mcols;
        hipLaunchKernelGGL(cost_kernel, dim3((total + 255) / 256), dim3(256), 0, stream,
                           logits, pred_bbox, target_bbox, target_labels, gcost);
    }
    hipLaunchKernelGGL(lsa_kernel, dim3(Bn), dim3(64), 0, stream,
                       logits, pred_bbox, target_bbox, target_labels,
                       gcost, use_gcost, src);
    hipLaunchKernelGGL(loss_kernel, dim3(Bn), dim3(256), 0, stream,
                       logits, pred_bbox, target_bbox, target_labels, src, partials);
    hipLaunchKernelGGL(finalize_kernel, dim3(1), dim3(1), 0, stream, partials, out);
}

// Round 12
// 96.684 us; speedup vs baseline: 1.0859x; 1.0859x over previous
//
#include <hip/hip_runtime.h>
#include <math.h>

#define Bn 32
#define Qn 300
#define Tn 64
#define Cn 2
#define Mcols Qn   /* LSA columns (queries) */
#define Nrows Tn   /* LSA rows (targets)   */
#define NSLOT 5    /* ceil(300/64) columns per lane */

#define CLS_SCALE_F 0.1f
#define BBOX_SCALE_D 5.0
#define GIOU_SCALE_D 2.0

typedef unsigned int uint2v __attribute__((ext_vector_type(2)));

// ---------------------------------------------------------------------------
// Lexicographic (value, pack) min reduction stages (rounds 5/8/9/10-proven).
// ---------------------------------------------------------------------------
template <int CTRL>
__device__ __forceinline__ void lexmin_dpp(double& bv, int& bp) {
    int lo = __builtin_amdgcn_update_dpp(0, __double2loint(bv), CTRL, 0xF, 0xF, true);
    int hi = __builtin_amdgcn_update_dpp(0, __double2hiint(bv), CTRL, 0xF, 0xF, true);
    int op = __builtin_amdgcn_update_dpp(0, bp,                 CTRL, 0xF, 0xF, true);
    double ov = __hiloint2double(hi, lo);
    if (ov < bv || (ov == bv && op < bp)) { bv = ov; bp = op; }
}
__device__ __forceinline__ void lexmin_shfl(double& bv, int& bp, int off) {
    double ov = __shfl_xor(bv, off);
    int    op = __shfl_xor(bp, off);
    if (ov < bv || (ov == bv && op < bp)) { bv = ov; bp = op; }
}
#if __has_builtin(__builtin_amdgcn_permlane16_swap) && __has_builtin(__builtin_amdgcn_permlane32_swap)
__device__ __forceinline__ void lexmin_pl16(double& bv, int& bp) {
    uint2v rlo = __builtin_amdgcn_permlane16_swap((unsigned)__double2loint(bv), (unsigned)__double2loint(bv), false, false);
    uint2v rhi = __builtin_amdgcn_permlane16_swap((unsigned)__double2hiint(bv), (unsigned)__double2hiint(bv), false, false);
    uint2v rpk = __builtin_amdgcn_permlane16_swap((unsigned)bp, (unsigned)bp, false, false);
    double av = __hiloint2double((int)rhi[0], (int)rlo[0]); int ap = (int)rpk[0];
    double bw = __hiloint2double((int)rhi[1], (int)rlo[1]); int bq = (int)rpk[1];
    if (av < bw || (av == bw && ap < bq)) { bv = av; bp = ap; } else { bv = bw; bp = bq; }
}
__device__ __forceinline__ void lexmin_pl32(double& bv, int& bp) {
    uint2v rlo = __builtin_amdgcn_permlane32_swap((unsigned)__double2loint(bv), (unsigned)__double2loint(bv), false, false);
    uint2v rhi = __builtin_amdgcn_permlane32_swap((unsigned)__double2hiint(bv), (unsigned)__double2hiint(bv), false, false);
    uint2v rpk = __builtin_amdgcn_permlane32_swap((unsigned)bp, (unsigned)bp, false, false);
    double av = __hiloint2double((int)rhi[0], (int)rlo[0]); int ap = (int)rpk[0];
    double bw = __hiloint2double((int)rhi[1], (int)rlo[1]); int bq = (int)rpk[1];
    if (av < bw || (av == bw && ap < bq)) { bv = av; bp = ap; } else { bv = bw; bp = bq; }
}
// f32 min-only stages for the warm-start pass (round-10-proven)
template <int CTRL>
__device__ __forceinline__ float dppmin_f32(float x) {
    int o = __builtin_amdgcn_update_dpp(0, __float_as_int(x), CTRL, 0xF, 0xF, true);
    return fminf(x, __int_as_float(o));
}
__device__ __forceinline__ float pl16min_f32(float x) {
    uint2v r = __builtin_amdgcn_permlane16_swap((unsigned)__float_as_int(x), (unsigned)__float_as_int(x), false, false);
    return fminf(__int_as_float((int)r[0]), __int_as_float((int)r[1]));
}
__device__ __forceinline__ float pl32min_f32(float x) {
    uint2v r = __builtin_amdgcn_permlane32_swap((unsigned)__float_as_int(x), (unsigned)__float_as_int(x), false, false);
    return fminf(__int_as_float((int)r[0]), __int_as_float((int)r[1]));
}
#else
__device__ __forceinline__ void lexmin_pl16(double& bv, int& bp) { lexmin_shfl(bv, bp, 16); }
__device__ __forceinline__ void lexmin_pl32(double& bv, int& bp) { lexmin_shfl(bv, bp, 32); }
template <int CTRL>
__device__ __forceinline__ float dppmin_f32(float x) {
    int o = __builtin_amdgcn_update_dpp(0, __float_as_int(x), CTRL, 0xF, 0xF, true);
    return fminf(x, __int_as_float(o));
}
__device__ __forceinline__ float pl16min_f32(float x) { return fminf(x, __shfl_xor(x, 16)); }
__device__ __forceinline__ float pl32min_f32(float x) { return fminf(x, __shfl_xor(x, 32)); }
#endif

// ---------------------------------------------------------------------------
// Cost kernel (massively parallel): cost[b][t][q] = L1 - p_class - giou (f32)
// ---------------------------------------------------------------------------
__global__ __launch_bounds__(256) void cost_kernel(
    const float* __restrict__ logits,        // [B][Q][C]
    const float* __restrict__ pred_bbox,     // [B][Q][4]
    const float* __restrict__ target_bbox,   // [B][T][4]
    const int*   __restrict__ target_labels, // [B][T]
    float* __restrict__ cost)                // [B][T][Q]
{
    int idx = blockIdx.x * blockDim.x + threadIdx.x;
    const int total = Bn * Nrows * Mcols;
    if (idx >= total) return;
    int q = idx % Mcols;
    int t = (idx / Mcols) % Nrows;
    int b = idx / (Mcols * Nrows);

    float l0 = logits[(b * Qn + q) * Cn + 0];
    float l1 = logits[(b * Qn + q) * Cn + 1];
    float mx = fmaxf(l0, l1);
    float e0 = expf(l0 - mx), e1 = expf(l1 - mx);
    float den = e0 + e1;
    float pce0 = e0 / den, pce1 = e1 / den;
    float cost_class = (target_labels[b * Tn + t] == 0) ? -pce0 : -pce1;

    const float* pb = pred_bbox + (b * Qn + q) * 4;
    const float* tb = target_bbox + (b * Tn + t) * 4;
    float pcx = pb[0], pcy = pb[1], pw = pb[2], ph = pb[3];
    float tcx = tb[0], tcy = tb[1], tw = tb[2], th = tb[3];
    float cost_bbox = fabsf(pcx - tcx) + fabsf(pcy - tcy) +
                      fabsf(pw - tw) + fabsf(ph - th);

    float p0 = pcx - 0.5f * pw, p1 = pcy - 0.5f * ph;
    float p2 = pcx + 0.5f * pw, p3 = pcy + 0.5f * ph;
    float t0 = tcx - 0.5f * tw, t1 = tcy - 0.5f * th;
    float t2 = tcx + 0.5f * tw, t3 = tcy + 0.5f * th;
    float area1 = (p2 - p0) * (p3 - p1);
    float area2 = (t2 - t0) * (t3 - t1);
    float ltx = fmaxf(p0, t0), lty = fmaxf(p1, t1);
    float rbx = fminf(p2, t2), rby = fminf(p3, t3);
    float iw = fmaxf(rbx - ltx, 0.0f), ih = fmaxf(rby - lty, 0.0f);
    float inter = iw * ih;
    float uni   = area1 + area2 - inter;
    float iou   = inter / uni;
    float ex0 = fminf(p0, t0), ey0 = fminf(p1, t1);
    float ex1 = fmaxf(p2, t2), ey1 = fmaxf(p3, t3);
    float ew = fmaxf(ex1 - ex0, 0.0f), eh = fmaxf(ey1 - ey0, 0.0f);
    float enc = ew * eh;
    float giou = iou - (enc - uni) / enc;

    cost[((size_t)b * Nrows + t) * Mcols + q] = cost_bbox + cost_class - giou;
}

// ---------------------------------------------------------------------------
// Fused LSA + per-batch loss kernel.
// Phase 0 — round-10-proven row-reduction warm start (u[i]=rowmin, greedy
//   assign if argmin column free; f32 min reduce + ballot/ctz argmin).
// Phase 1 — rounds-9/10-proven JV Dijkstra for deferred rows with feasible
//   warm duals => optimal assignment = reference's (unique optimum;
//   validated absmax 0.0 in round 10).
// Tail — per-batch loss partials computed in-kernel from the wave-resident
//   assignment (CE over queries, L1+GIoU on matched pairs), reduced with a
//   deterministic fixed-order shfl_xor butterfly in f64.
// ---------------------------------------------------------------------------
__global__ __launch_bounds__(64) void lsa_kernel(
    const float* __restrict__ logits,
    const float* __restrict__ pred_bbox,
    const float* __restrict__ target_bbox,
    const int*   __restrict__ target_labels,
    const float* __restrict__ gcost,   // [B][T][Q] or unused
    int use_gcost,
    double* __restrict__ partials)     // [B][4]
{
    const int b   = blockIdx.x;
    const int tid = threadIdx.x;

    __shared__ float cst[Nrows * Mcols];   // 76800 B
    __shared__ int   p_lds[Mcols + 1];
    __shared__ int   way_lds[Mcols + 1];
    __shared__ float tb4[Tn * 4];
    __shared__ int   tlab[Tn];
    __shared__ int   clsB[Qn];
    __shared__ int   srcB[Tn];

    for (int j = tid; j <= Mcols; j += 64) { p_lds[j] = 0; way_lds[j] = 0; }
    srcB[tid] = tid;   // identity fallback; overwritten by emit

    if (use_gcost) {
        const float* gb = gcost + (size_t)b * Nrows * Mcols;
        for (int k = 0; k < 75; ++k) {
            __builtin_amdgcn_global_load_lds(
                (const __attribute__((address_space(1))) void*)(gb + k * 256 + tid * 4),
                (__attribute__((address_space(3))) void*)(cst + k * 256),
                16, 0, 0);
        }
    } else {
        for (int k = tid; k < Tn * 4; k += 64) tb4[k] = target_bbox[b * Tn * 4 + k];
        for (int k = tid; k < Tn; k += 64)     tlab[k] = target_labels[b * Tn + k];
        __syncthreads();
        for (int qt = 0; qt < NSLOT; ++qt) {
            int q = qt * 64 + tid;
            if (q < Qn) {
                float l0 = logits[(b * Qn + q) * Cn + 0];
                float l1 = logits[(b * Qn + q) * Cn + 1];
                float mx = fmaxf(l0, l1);
                float e0 = expf(l0 - mx), e1 = expf(l1 - mx);
                float den = e0 + e1;
                float pce0 = e0 / den, pce1 = e1 / den;

                const float* pb = pred_bbox + (b * Qn + q) * 4;
                float pcx = pb[0], pcy = pb[1], pw = pb[2], ph = pb[3];
                float p0 = pcx - 0.5f * pw, p1 = pcy - 0.5f * ph;
                float p2 = pcx + 0.5f * pw, p3 = pcy + 0.5f * ph;
                float area1 = (p2 - p0) * (p3 - p1);

                for (int t = 0; t < Tn; ++t) {
                    float tcx = tb4[t * 4 + 0], tcy = tb4[t * 4 + 1];
                    float tw  = tb4[t * 4 + 2], th  = tb4[t * 4 + 3];
                    float cost_bbox = fabsf(pcx - tcx) + fabsf(pcy - tcy) +
                                      fabsf(pw - tw) + fabsf(ph - th);
                    float cost_class = (tlab[t] == 0) ? -pce0 : -pce1;

                    float t0 = tcx - 0.5f * tw, t1 = tcy - 0.5f * th;
                    float t2 = tcx + 0.5f * tw, t3 = tcy + 0.5f * th;
                    float area2 = (t2 - t0) * (t3 - t1);
                    float ltx = fmaxf(p0, t0), lty = fmaxf(p1, t1);
                    float rbx = fminf(p2, t2), rby = fminf(p3, t3);
                    float iw = fmaxf(rbx - ltx, 0.0f), ih = fmaxf(rby - lty, 0.0f);
                    float inter = iw * ih;
                    float uni   = area1 + area2 - inter;
                    float iou   = inter / uni;
                    float ex0 = fminf(p0, t0), ey0 = fminf(p1, t1);
                    float ex1 = fmaxf(p2, t2), ey1 = fmaxf(p3, t3);
                    float ew = fmaxf(ex1 - ex0, 0.0f), eh = fmaxf(ey1 - ey0, 0.0f);
                    float enc = ew * eh;
                    float giou = iou - (enc - uni) / enc;

                    cst[t * Mcols + q] = cost_bbox + cost_class - giou;
                }
            }
        }
    }
    __syncthreads();   // tile + bookkeeping visible (drains vmcnt for DMA)

    // ---- registerized hot state: lane owns columns j-1 = s*64 + tid ----
    double v_[NSLOT], minv_[NSLOT];
    int    pcs_[NSLOT];
    double u_ = 0.0;
    unsigned usedM;
    #pragma unroll
    for (int s = 0; s < NSLOT; ++s) v_[s] = 0.0;

    const bool valid_[NSLOT] = {
        true, true, true, true, (4 * 64 + tid) < Mcols
    };

    // ---- Phase 0: row-reduction warm start (round-10-proven form) ----
    unsigned long long matchedRows = 0ULL;
    for (int i = 1; i <= Nrows; ++i) {
        float bc = INFINITY; int bj = 1;
        #pragma unroll
        for (int s = 0; s < NSLOT; ++s) {
            int jj = s * 64 + tid;
            float c = (jj < Mcols) ? cst[(i - 1) * Mcols + jj] : INFINITY;
            if (c < bc) { bc = c; bj = jj + 1; }
        }
        float gm = bc;
        gm = dppmin_f32<0xB1>(gm);     // quad_perm xor1
        gm = dppmin_f32<0x4E>(gm);     // quad_perm xor2
        gm = dppmin_f32<0x124>(gm);    // row_ror:4
        gm = dppmin_f32<0x128>(gm);    // row_ror:8
        gm = pl16min_f32(gm);          // 16-lane row swap
        gm = pl32min_f32(gm);          // 32-lane half swap

        unsigned long long bal = __ballot(bc == gm);
        int flane = (int)__builtin_ctzll(bal);      // bal != 0 guaranteed
        int jstar = __shfl(bj, flane);
        int pj = p_lds[jstar];
        if (pj == 0) {
            if (tid == 0) p_lds[jstar] = i;
            matchedRows |= (1ULL << (i - 1));
        }
        if (tid == i - 1) u_ = (double)gm;   // u[i] = rowmin (exact f64 of f32)
        __syncthreads();
    }

    // ---- Phase 1: JV Dijkstra for deferred rows (rounds 9/10-proven) ----
    for (int i = 1; i <= Nrows; ++i) {
        if ((matchedRows >> (i - 1)) & 1ULL) continue;

        #pragma unroll
        for (int s = 0; s < NSLOT; ++s) {
            int j = s * 64 + tid + 1;
            pcs_[s] = valid_[s] ? p_lds[j] : 0;
            minv_[s] = INFINITY;
        }
        usedM = 0;
        bool inTree = (tid == i - 1);   // row i is the tree root
        int j0cur = 0;
        int j1 = 0, pj1 = 0;

        // preload row i costs + u[i]
        double ui0 = __shfl(u_, i - 1);
        float c5[NSLOT];
        #pragma unroll
        for (int s = 0; s < NSLOT; ++s) {
            int jj = s * 64 + tid; if (jj >= Mcols) jj = 0;
            c5[s] = cst[(i - 1) * Mcols + jj];
        }

        for (int step = 0; step <= Mcols + 1; ++step) {
            // relax free columns; lane-local lex argmin (s asc => j asc)
            double bestv = INFINITY;
            int bestpack = 0x7fffffff;   // (j<<8)|p[j]
            #pragma unroll
            for (int s = 0; s < NSLOT; ++s) {
                if (valid_[s] && !((usedM >> s) & 1u)) {
                    int j = s * 64 + tid + 1;
                    double cur = ((double)c5[s] - ui0) - v_[s];
                    if (cur < minv_[s]) { minv_[s] = cur; way_lds[j] = j0cur; }
                    if (minv_[s] < bestv) {
                        bestv = minv_[s];
                        bestpack = (j << 8) | pcs_[s];
                    }
                }
            }
            // wave-wide lex (value, j) argmin (proven stages)
            lexmin_dpp<0xB1>(bestv, bestpack);    // quad_perm xor1
            lexmin_dpp<0x4E>(bestv, bestpack);    // quad_perm xor2
            lexmin_dpp<0x124>(bestv, bestpack);   // row_ror:4
            lexmin_dpp<0x128>(bestv, bestpack);   // row_ror:8
            lexmin_pl16(bestv, bestpack);         // 16-lane row swap
            lexmin_pl32(bestv, bestpack);         // 32-lane half swap

            double delta = bestv;
            j1  = bestpack >> 8;
            pj1 = bestpack & 0xff;

            bool brk = (pj1 == 0);
            if (!brk) {
                // prefetch next row's u and costs; latency overlaps dual update
                ui0 = __shfl(u_, pj1 - 1);
                #pragma unroll
                for (int s = 0; s < NSLOT; ++s) {
                    int jj = s * 64 + tid; if (jj >= Mcols) jj = 0;
                    c5[s] = cst[(pj1 - 1) * Mcols + jj];
                }
            }

            // dual update (reference order; usedM excludes j1 this step)
            if (inTree) u_ += delta;
            #pragma unroll
            for (int s = 0; s < NSLOT; ++s) {
                if ((usedM >> s) & 1u) v_[s] -= delta;
                else if (valid_[s])    minv_[s] -= delta;
            }

            if (brk) break;

            if (((j1 - 1) & 63) == tid) usedM |= 1u << ((j1 - 1) >> 6);
            if (tid == pj1 - 1) inTree = true;
            j0cur = j1;
        }

        __syncthreads();   // way_lds stores visible before augment
        if (tid == 0) {
            int jj = j1;
            for (int st = 0; st < Mcols + 2 && jj != 0; ++st) {
                int jn = way_lds[jj];
                p_lds[jj] = (jn == 0) ? i : p_lds[jn];
                jj = jn;
            }
        }
        __syncthreads();   // p_lds updated before next snapshot
    }

    // ---- emit assignment into LDS (guarded) ----
    for (int j = tid + 1; j <= Mcols; j += 64) {
        int pi = p_lds[j];
        if (pi > 0 && pi <= Nrows) srcB[pi - 1] = j - 1;
    }
    for (int q = tid; q < Qn; q += 64) clsB[q] = Cn - 1;   // "no object"
    __syncthreads();

    // ---- fused loss tail ----
    {
        unsigned qm = (unsigned)srcB[tid];
        if (qm >= Qn) qm = 0;                               // clamp (defensive)
        clsB[qm] = target_labels[b * Tn + tid];
    }
    __syncthreads();

    double s_wnll = 0.0, s_w = 0.0, s_l1 = 0.0, s_giou = 0.0;

    for (int q = tid; q < Qn; q += 64) {
        float l0 = logits[(b * Qn + q) * Cn + 0];
        float l1 = logits[(b * Qn + q) * Cn + 1];
        float mx = fmaxf(l0, l1);
        float lse = mx + logf(expf(l0 - mx) + expf(l1 - mx));
        int tc = clsB[q];
        float lt = (tc == 0) ? l0 : l1;
        float nll = lse - lt;
        float wt = (tc == Cn - 1) ? CLS_SCALE_F : 1.0f;
        s_wnll += (double)(wt * nll);
        s_w    += (double)wt;
    }

    {
        int t = tid;                                        // Tn == 64 lanes
        unsigned q = (unsigned)srcB[t];
        if (q >= Qn) q = 0;                                 // clamp (defensive)
        const float* pb = pred_bbox + ((size_t)b * Qn + q) * 4;
        const float* tb = target_bbox + ((size_t)b * Tn + t) * 4;
        float pcx = pb[0], pcy = pb[1], pw = pb[2], ph = pb[3];
        float tcx = tb[0], tcy = tb[1], tw = tb[2], th = tb[3];
        s_l1 = (double)(fabsf(pcx - tcx) + fabsf(pcy - tcy) +
                        fabsf(pw - tw) + fabsf(ph - th));

        float p0 = pcx - 0.5f * pw, p1 = pcy - 0.5f * ph;
        float p2 = pcx + 0.5f * pw, p3 = pcy + 0.5f * ph;
        float t0 = tcx - 0.5f * tw, t1 = tcy - 0.5f * th;
        float t2 = tcx + 0.5f * tw, t3 = tcy + 0.5f * th;
        float area1 = (p2 - p0) * (p3 - p1);
        float area2 = (t2 - t0) * (t3 - t1);
        float ltx = fmaxf(p0, t0), lty = fmaxf(p1, t1);
        float rbx = fminf(p2, t2), rby = fminf(p3, t3);
        float iw = fmaxf(rbx - ltx, 0.0f), ih = fmaxf(rby - lty, 0.0f);
        float inter = iw * ih;
        float uni = area1 + area2 - inter;
        float iou = inter / uni;
        float ex0 = fminf(p0, t0), ey0 = fminf(p1, t1);
        float ex1 = fmaxf(p2, t2), ey1 = fmaxf(p3, t3);
        float ew = fmaxf(ex1 - ex0, 0.0f), eh = fmaxf(ey1 - ey0, 0.0f);
        float enc = ew * eh;
        float giou = iou - (enc - uni) / enc;
        s_giou = (double)(1.0f - giou);
    }

    // deterministic fixed-order wave butterfly sum (same result every replay)
    double vals[4] = { s_wnll, s_w, s_l1, s_giou };
    #pragma unroll
    for (int k = 0; k < 4; ++k) {
        double v = vals[k];
        #pragma unroll
        for (int off = 32; off > 0; off >>= 1) v += __shfl_xor(v, off);
        if (tid == 0) partials[b * 4 + k] = v;
    }
}

// ---------------------------------------------------------------------------
__global__ void finalize_kernel(const double* __restrict__ partials,
                                float* __restrict__ out)
{
    if (threadIdx.x != 0 || blockIdx.x != 0) return;
    double wnll = 0.0, w = 0.0, l1 = 0.0, gi = 0.0;
    for (int b = 0; b < Bn; ++b) {
        wnll += partials[b * 4 + 0];
        w    += partials[b * 4 + 1];
        l1   += partials[b * 4 + 2];
        gi   += partials[b * 4 + 3];
    }
    double nb = (double)(Bn * Tn);
    double loss = wnll / w + BBOX_SCALE_D * (l1 / nb) + GIOU_SCALE_D * (gi / nb);
    out[0] = (float)loss;
}

// ---------------------------------------------------------------------------
extern "C" void kernel_launch(void* const* d_in, const int* in_sizes, int n_in,
                              void* d_out, int out_size, void* d_ws, size_t ws_size,
                              hipStream_t stream)
{
    const float* logits        = (const float*)d_in[0];
    const float* pred_bbox     = (const float*)d_in[1];
    const float* target_bbox   = (const float*)d_in[2];
    const int*   target_labels = (const int*)d_in[3];
    float* out = (float*)d_out;

    char* ws = (char*)d_ws;
    double* partials = (double*)(ws + 8448);               // 1024 B
    float* gcost = (float*)(ws + 16384);                   // 2457600 B (optional)

    const size_t cost_bytes = (size_t)Bn * Nrows * Mcols * sizeof(float);
    const int use_gcost = (ws_size >= 16384 + cost_bytes) ? 1 : 0;

    if (use_gcost) {
        const int total = Bn * Nrows * Mcols;
        hipLaunchKernelGGL(cost_kernel, dim3((total + 255) / 256), dim3(256), 0, stream,
                           logits, pred_bbox, target_bbox, target_labels, gcost);
    }
    hipLaunchKernelGGL(lsa_kernel, dim3(Bn), dim3(64), 0, stream,
                       logits, pred_bbox, target_bbox, target_labels,
                       gcost, use_gcost, partials);
    hipLaunchKernelGGL(finalize_kernel, dim3(1), dim3(1), 0, stream, partials, out);
}

// Round 14
// 95.599 us; speedup vs baseline: 1.0982x; 1.0113x over previous
//
#include <hip/hip_runtime.h>
#include <math.h>

#define Bn 32
#define Qn 300
#define Tn 64
#define Cn 2
#define Mcols Qn   /* LSA columns (queries) */
#define Nrows Tn   /* LSA rows (targets)   */
#define NSLOT 5    /* ceil(300/64) columns per lane */

#define CLS_SCALE_F 0.1f
#define BBOX_SCALE_D 5.0
#define GIOU_SCALE_D 2.0

typedef unsigned int uint2v __attribute__((ext_vector_type(2)));

// ---------------------------------------------------------------------------
// Lexicographic (value, pack) min reduction stages (rounds 5/8/9/10-proven).
// ---------------------------------------------------------------------------
template <int CTRL>
__device__ __forceinline__ void lexmin_dpp(double& bv, int& bp) {
    int lo = __builtin_amdgcn_update_dpp(0, __double2loint(bv), CTRL, 0xF, 0xF, true);
    int hi = __builtin_amdgcn_update_dpp(0, __double2hiint(bv), CTRL, 0xF, 0xF, true);
    int op = __builtin_amdgcn_update_dpp(0, bp,                 CTRL, 0xF, 0xF, true);
    double ov = __hiloint2double(hi, lo);
    if (ov < bv || (ov == bv && op < bp)) { bv = ov; bp = op; }
}
__device__ __forceinline__ void lexmin_shfl(double& bv, int& bp, int off) {
    double ov = __shfl_xor(bv, off);
    int    op = __shfl_xor(bp, off);
    if (ov < bv || (ov == bv && op < bp)) { bv = ov; bp = op; }
}
#if __has_builtin(__builtin_amdgcn_permlane16_swap) && __has_builtin(__builtin_amdgcn_permlane32_swap)
__device__ __forceinline__ void lexmin_pl16(double& bv, int& bp) {
    uint2v rlo = __builtin_amdgcn_permlane16_swap((unsigned)__double2loint(bv), (unsigned)__double2loint(bv), false, false);
    uint2v rhi = __builtin_amdgcn_permlane16_swap((unsigned)__double2hiint(bv), (unsigned)__double2hiint(bv), false, false);
    uint2v rpk = __builtin_amdgcn_permlane16_swap((unsigned)bp, (unsigned)bp, false, false);
    double av = __hiloint2double((int)rhi[0], (int)rlo[0]); int ap = (int)rpk[0];
    double bw = __hiloint2double((int)rhi[1], (int)rlo[1]); int bq = (int)rpk[1];
    if (av < bw || (av == bw && ap < bq)) { bv = av; bp = ap; } else { bv = bw; bp = bq; }
}
__device__ __forceinline__ void lexmin_pl32(double& bv, int& bp) {
    uint2v rlo = __builtin_amdgcn_permlane32_swap((unsigned)__double2loint(bv), (unsigned)__double2loint(bv), false, false);
    uint2v rhi = __builtin_amdgcn_permlane32_swap((unsigned)__double2hiint(bv), (unsigned)__double2hiint(bv), false, false);
    uint2v rpk = __builtin_amdgcn_permlane32_swap((unsigned)bp, (unsigned)bp, false, false);
    double av = __hiloint2double((int)rhi[0], (int)rlo[0]); int ap = (int)rpk[0];
    double bw = __hiloint2double((int)rhi[1], (int)rlo[1]); int bq = (int)rpk[1];
    if (av < bw || (av == bw && ap < bq)) { bv = av; bp = ap; } else { bv = bw; bp = bq; }
}
// f32 min-only stages for the warm-start pass (round-10-proven)
template <int CTRL>
__device__ __forceinline__ float dppmin_f32(float x) {
    int o = __builtin_amdgcn_update_dpp(0, __float_as_int(x), CTRL, 0xF, 0xF, true);
    return fminf(x, __int_as_float(o));
}
__device__ __forceinline__ float pl16min_f32(float x) {
    uint2v r = __builtin_amdgcn_permlane16_swap((unsigned)__float_as_int(x), (unsigned)__float_as_int(x), false, false);
    return fminf(__int_as_float((int)r[0]), __int_as_float((int)r[1]));
}
__device__ __forceinline__ float pl32min_f32(float x) {
    uint2v r = __builtin_amdgcn_permlane32_swap((unsigned)__float_as_int(x), (unsigned)__float_as_int(x), false, false);
    return fminf(__int_as_float((int)r[0]), __int_as_float((int)r[1]));
}
#else
__device__ __forceinline__ void lexmin_pl16(double& bv, int& bp) { lexmin_shfl(bv, bp, 16); }
__device__ __forceinline__ void lexmin_pl32(double& bv, int& bp) { lexmin_shfl(bv, bp, 32); }
template <int CTRL>
__device__ __forceinline__ float dppmin_f32(float x) {
    int o = __builtin_amdgcn_update_dpp(0, __float_as_int(x), CTRL, 0xF, 0xF, true);
    return fminf(x, __int_as_float(o));
}
__device__ __forceinline__ float pl16min_f32(float x) { return fminf(x, __shfl_xor(x, 16)); }
__device__ __forceinline__ float pl32min_f32(float x) { return fminf(x, __shfl_xor(x, 32)); }
#endif

// ---------------------------------------------------------------------------
// Cost kernel (massively parallel): cost[b][t][q] = L1 - p_class - giou (f32)
// Also zeroes the last-block-done counter for this call (runs before lsa
// in-stream, so the counter is 0 before any lsa block's atomicAdd).
// ---------------------------------------------------------------------------
__global__ __launch_bounds__(256) void cost_kernel(
    const float* __restrict__ logits,        // [B][Q][C]
    const float* __restrict__ pred_bbox,     // [B][Q][4]
    const float* __restrict__ target_bbox,   // [B][T][4]
    const int*   __restrict__ target_labels, // [B][T]
    float* __restrict__ cost,                // [B][T][Q]
    unsigned* __restrict__ counter)
{
    int idx = blockIdx.x * blockDim.x + threadIdx.x;
    if (idx == 0) *counter = 0u;             // re-zeroed every call (replay-safe)
    const int total = Bn * Nrows * Mcols;
    if (idx >= total) return;
    int q = idx % Mcols;
    int t = (idx / Mcols) % Nrows;
    int b = idx / (Mcols * Nrows);

    float l0 = logits[(b * Qn + q) * Cn + 0];
    float l1 = logits[(b * Qn + q) * Cn + 1];
    float mx = fmaxf(l0, l1);
    float e0 = expf(l0 - mx), e1 = expf(l1 - mx);
    float den = e0 + e1;
    float pce0 = e0 / den, pce1 = e1 / den;
    float cost_class = (target_labels[b * Tn + t] == 0) ? -pce0 : -pce1;

    const float* pb = pred_bbox + (b * Qn + q) * 4;
    const float* tb = target_bbox + (b * Tn + t) * 4;
    float pcx = pb[0], pcy = pb[1], pw = pb[2], ph = pb[3];
    float tcx = tb[0], tcy = tb[1], tw = tb[2], th = tb[3];
    float cost_bbox = fabsf(pcx - tcx) + fabsf(pcy - tcy) +
                      fabsf(pw - tw) + fabsf(ph - th);

    float p0 = pcx - 0.5f * pw, p1 = pcy - 0.5f * ph;
    float p2 = pcx + 0.5f * pw, p3 = pcy + 0.5f * ph;
    float t0 = tcx - 0.5f * tw, t1 = tcy - 0.5f * th;
    float t2 = tcx + 0.5f * tw, t3 = tcy + 0.5f * th;
    float area1 = (p2 - p0) * (p3 - p1);
    float area2 = (t2 - t0) * (t3 - t1);
    float ltx = fmaxf(p0, t0), lty = fmaxf(p1, t1);
    float rbx = fminf(p2, t2), rby = fminf(p3, t3);
    float iw = fmaxf(rbx - ltx, 0.0f), ih = fmaxf(rby - lty, 0.0f);
    float inter = iw * ih;
    float uni   = area1 + area2 - inter;
    float iou   = inter / uni;
    float ex0 = fminf(p0, t0), ey0 = fminf(p1, t1);
    float ex1 = fmaxf(p2, t2), ey1 = fmaxf(p3, t3);
    float ew = fmaxf(ex1 - ex0, 0.0f), eh = fmaxf(ey1 - ey0, 0.0f);
    float enc = ew * eh;
    float giou = iou - (enc - uni) / enc;

    cost[((size_t)b * Nrows + t) * Mcols + q] = cost_bbox + cost_class - giou;
}

// ---------------------------------------------------------------------------
// Fused LSA + per-batch loss kernel (round-12-proven Phase 0 / Phase 1 /
// loss tail), plus last-block-done finalize: the block whose atomicAdd
// observes prev == Bn-1 reads all partials (fixed order => deterministic)
// and writes the scalar loss. Device-scope fences handle cross-XCD L2.
// ---------------------------------------------------------------------------
__global__ __launch_bounds__(64) void lsa_kernel(
    const float* __restrict__ logits,
    const float* __restrict__ pred_bbox,
    const float* __restrict__ target_bbox,
    const int*   __restrict__ target_labels,
    const float* __restrict__ gcost,   // [B][T][Q] or unused
    int use_gcost,
    double* __restrict__ partials,     // [B][4]
    unsigned* __restrict__ counter,
    int do_finalize,
    float* __restrict__ out)
{
    const int b   = blockIdx.x;
    const int tid = threadIdx.x;

    __shared__ float cst[Nrows * Mcols];   // 76800 B
    __shared__ int   p_lds[Mcols + 1];
    __shared__ int   way_lds[Mcols + 1];
    __shared__ float tb4[Tn * 4];
    __shared__ int   tlab[Tn];
    __shared__ int   clsB[Qn];
    __shared__ int   srcB[Tn];

    for (int j = tid; j <= Mcols; j += 64) { p_lds[j] = 0; way_lds[j] = 0; }
    srcB[tid] = tid;   // identity fallback; overwritten by emit

    if (use_gcost) {
        const float* gb = gcost + (size_t)b * Nrows * Mcols;
        for (int k = 0; k < 75; ++k) {
            __builtin_amdgcn_global_load_lds(
                (const __attribute__((address_space(1))) void*)(gb + k * 256 + tid * 4),
                (__attribute__((address_space(3))) void*)(cst + k * 256),
                16, 0, 0);
        }
    } else {
        for (int k = tid; k < Tn * 4; k += 64) tb4[k] = target_bbox[b * Tn * 4 + k];
        for (int k = tid; k < Tn; k += 64)     tlab[k] = target_labels[b * Tn + k];
        __syncthreads();
        for (int qt = 0; qt < NSLOT; ++qt) {
            int q = qt * 64 + tid;
            if (q < Qn) {
                float l0 = logits[(b * Qn + q) * Cn + 0];
                float l1 = logits[(b * Qn + q) * Cn + 1];
                float mx = fmaxf(l0, l1);
                float e0 = expf(l0 - mx), e1 = expf(l1 - mx);
                float den = e0 + e1;
                float pce0 = e0 / den, pce1 = e1 / den;

                const float* pb = pred_bbox + (b * Qn + q) * 4;
                float pcx = pb[0], pcy = pb[1], pw = pb[2], ph = pb[3];
                float p0 = pcx - 0.5f * pw, p1 = pcy - 0.5f * ph;
                float p2 = pcx + 0.5f * pw, p3 = pcy + 0.5f * ph;
                float area1 = (p2 - p0) * (p3 - p1);

                for (int t = 0; t < Tn; ++t) {
                    float tcx = tb4[t * 4 + 0], tcy = tb4[t * 4 + 1];
                    float tw  = tb4[t * 4 + 2], th  = tb4[t * 4 + 3];
                    float cost_bbox = fabsf(pcx - tcx) + fabsf(pcy - tcy) +
                                      fabsf(pw - tw) + fabsf(ph - th);
                    float cost_class = (tlab[t] == 0) ? -pce0 : -pce1;

                    float t0 = tcx - 0.5f * tw, t1 = tcy - 0.5f * th;
                    float t2 = tcx + 0.5f * tw, t3 = tcy + 0.5f * th;
                    float area2 = (t2 - t0) * (t3 - t1);
                    float ltx = fmaxf(p0, t0), lty = fmaxf(p1, t1);
                    float rbx = fminf(p2, t2), rby = fminf(p3, t3);
                    float iw = fmaxf(rbx - ltx, 0.0f), ih = fmaxf(rby - lty, 0.0f);
                    float inter = iw * ih;
                    float uni   = area1 + area2 - inter;
                    float iou   = inter / uni;
                    float ex0 = fminf(p0, t0), ey0 = fminf(p1, t1);
                    float ex1 = fmaxf(p2, t2), ey1 = fmaxf(p3, t3);
                    float ew = fmaxf(ex1 - ex0, 0.0f), eh = fmaxf(ey1 - ey0, 0.0f);
                    float enc = ew * eh;
                    float giou = iou - (enc - uni) / enc;

                    cst[t * Mcols + q] = cost_bbox + cost_class - giou;
                }
            }
        }
    }
    __syncthreads();   // tile + bookkeeping visible (drains vmcnt for DMA)

    // ---- registerized hot state: lane owns columns j-1 = s*64 + tid ----
    double v_[NSLOT], minv_[NSLOT];
    int    pcs_[NSLOT];
    double u_ = 0.0;
    unsigned usedM;
    #pragma unroll
    for (int s = 0; s < NSLOT; ++s) v_[s] = 0.0;

    const bool valid_[NSLOT] = {
        true, true, true, true, (4 * 64 + tid) < Mcols
    };

    // ---- Phase 0: row-reduction warm start (round-10/12-proven form) ----
    unsigned long long matchedRows = 0ULL;
    for (int i = 1; i <= Nrows; ++i) {
        float bc = INFINITY; int bj = 1;
        #pragma unroll
        for (int s = 0; s < NSLOT; ++s) {
            int jj = s * 64 + tid;
            float c = (jj < Mcols) ? cst[(i - 1) * Mcols + jj] : INFINITY;
            if (c < bc) { bc = c; bj = jj + 1; }
        }
        float gm = bc;
        gm = dppmin_f32<0xB1>(gm);     // quad_perm xor1
        gm = dppmin_f32<0x4E>(gm);     // quad_perm xor2
        gm = dppmin_f32<0x124>(gm);    // row_ror:4
        gm = dppmin_f32<0x128>(gm);    // row_ror:8
        gm = pl16min_f32(gm);          // 16-lane row swap
        gm = pl32min_f32(gm);          // 32-lane half swap

        unsigned long long bal = __ballot(bc == gm);
        int flane = (int)__builtin_ctzll(bal);      // bal != 0 guaranteed
        int jstar = __shfl(bj, flane);
        int pj = p_lds[jstar];
        if (pj == 0) {
            if (tid == 0) p_lds[jstar] = i;
            matchedRows |= (1ULL << (i - 1));
        }
        if (tid == i - 1) u_ = (double)gm;   // u[i] = rowmin (exact f64 of f32)
        __syncthreads();
    }

    // ---- Phase 1: JV Dijkstra for deferred rows (rounds 9/10/12-proven) ----
    for (int i = 1; i <= Nrows; ++i) {
        if ((matchedRows >> (i - 1)) & 1ULL) continue;

        #pragma unroll
        for (int s = 0; s < NSLOT; ++s) {
            int j = s * 64 + tid + 1;
            pcs_[s] = valid_[s] ? p_lds[j] : 0;
            minv_[s] = INFINITY;
        }
        usedM = 0;
        bool inTree = (tid == i - 1);   // row i is the tree root
        int j0cur = 0;
        int j1 = 0, pj1 = 0;

        // preload row i costs + u[i]
        double ui0 = __shfl(u_, i - 1);
        float c5[NSLOT];
        #pragma unroll
        for (int s = 0; s < NSLOT; ++s) {
            int jj = s * 64 + tid; if (jj >= Mcols) jj = 0;
            c5[s] = cst[(i - 1) * Mcols + jj];
        }

        for (int step = 0; step <= Mcols + 1; ++step) {
            // relax free columns; lane-local lex argmin (s asc => j asc)
            double bestv = INFINITY;
            int bestpack = 0x7fffffff;   // (j<<8)|p[j]
            #pragma unroll
            for (int s = 0; s < NSLOT; ++s) {
                if (valid_[s] && !((usedM >> s) & 1u)) {
                    int j = s * 64 + tid + 1;
                    double cur = ((double)c5[s] - ui0) - v_[s];
                    if (cur < minv_[s]) { minv_[s] = cur; way_lds[j] = j0cur; }
                    if (minv_[s] < bestv) {
                        bestv = minv_[s];
                        bestpack = (j << 8) | pcs_[s];
                    }
                }
            }
            // wave-wide lex (value, j) argmin (proven stages)
            lexmin_dpp<0xB1>(bestv, bestpack);    // quad_perm xor1
            lexmin_dpp<0x4E>(bestv, bestpack);    // quad_perm xor2
            lexmin_dpp<0x124>(bestv, bestpack);   // row_ror:4
            lexmin_dpp<0x128>(bestv, bestpack);   // row_ror:8
            lexmin_pl16(bestv, bestpack);         // 16-lane row swap
            lexmin_pl32(bestv, bestpack);         // 32-lane half swap

            double delta = bestv;
            j1  = bestpack >> 8;
            pj1 = bestpack & 0xff;

            bool brk = (pj1 == 0);
            if (!brk) {
                // prefetch next row's u and costs; latency overlaps dual update
                ui0 = __shfl(u_, pj1 - 1);
                #pragma unroll
                for (int s = 0; s < NSLOT; ++s) {
                    int jj = s * 64 + tid; if (jj >= Mcols) jj = 0;
                    c5[s] = cst[(pj1 - 1) * Mcols + jj];
                }
            }

            // dual update (reference order; usedM excludes j1 this step)
            if (inTree) u_ += delta;
            #pragma unroll
            for (int s = 0; s < NSLOT; ++s) {
                if ((usedM >> s) & 1u) v_[s] -= delta;
                else if (valid_[s])    minv_[s] -= delta;
            }

            if (brk) break;

            if (((j1 - 1) & 63) == tid) usedM |= 1u << ((j1 - 1) >> 6);
            if (tid == pj1 - 1) inTree = true;
            j0cur = j1;
        }

        __syncthreads();   // way_lds stores visible before augment
        if (tid == 0) {
            int jj = j1;
            for (int st = 0; st < Mcols + 2 && jj != 0; ++st) {
                int jn = way_lds[jj];
                p_lds[jj] = (jn == 0) ? i : p_lds[jn];
                jj = jn;
            }
        }
        __syncthreads();   // p_lds updated before next snapshot
    }

    // ---- emit assignment into LDS (guarded) ----
    for (int j = tid + 1; j <= Mcols; j += 64) {
        int pi = p_lds[j];
        if (pi > 0 && pi <= Nrows) srcB[pi - 1] = j - 1;
    }
    for (int q = tid; q < Qn; q += 64) clsB[q] = Cn - 1;   // "no object"
    __syncthreads();

    // ---- fused loss tail (round-12-proven) ----
    {
        unsigned qm = (unsigned)srcB[tid];
        if (qm >= Qn) qm = 0;                               // clamp (defensive)
        clsB[qm] = target_labels[b * Tn + tid];
    }
    __syncthreads();

    double s_wnll = 0.0, s_w = 0.0, s_l1 = 0.0, s_giou = 0.0;

    for (int q = tid; q < Qn; q += 64) {
        float l0 = logits[(b * Qn + q) * Cn + 0];
        float l1 = logits[(b * Qn + q) * Cn + 1];
        float mx = fmaxf(l0, l1);
        float lse = mx + logf(expf(l0 - mx) + expf(l1 - mx));
        int tc = clsB[q];
        float lt = (tc == 0) ? l0 : l1;
        float nll = lse - lt;
        float wt = (tc == Cn - 1) ? CLS_SCALE_F : 1.0f;
        s_wnll += (double)(wt * nll);
        s_w    += (double)wt;
    }

    {
        int t = tid;                                        // Tn == 64 lanes
        unsigned q = (unsigned)srcB[t];
        if (q >= Qn) q = 0;                                 // clamp (defensive)
        const float* pb = pred_bbox + ((size_t)b * Qn + q) * 4;
        const float* tb = target_bbox + ((size_t)b * Tn + t) * 4;
        float pcx = pb[0], pcy = pb[1], pw = pb[2], ph = pb[3];
        float tcx = tb[0], tcy = tb[1], tw = tb[2], th = tb[3];
        s_l1 = (double)(fabsf(pcx - tcx) + fabsf(pcy - tcy) +
                        fabsf(pw - tw) + fabsf(ph - th));

        float p0 = pcx - 0.5f * pw, p1 = pcy - 0.5f * ph;
        float p2 = pcx + 0.5f * pw, p3 = pcy + 0.5f * ph;
        float t0 = tcx - 0.5f * tw, t1 = tcy - 0.5f * th;
        float t2 = tcx + 0.5f * tw, t3 = tcy + 0.5f * th;
        float area1 = (p2 - p0) * (p3 - p1);
        float area2 = (t2 - t0) * (t3 - t1);
        float ltx = fmaxf(p0, t0), lty = fmaxf(p1, t1);
        float rbx = fminf(p2, t2), rby = fminf(p3, t3);
        float iw = fmaxf(rbx - ltx, 0.0f), ih = fmaxf(rby - lty, 0.0f);
        float inter = iw * ih;
        float uni = area1 + area2 - inter;
        float iou = inter / uni;
        float ex0 = fminf(p0, t0), ey0 = fminf(p1, t1);
        float ex1 = fmaxf(p2, t2), ey1 = fmaxf(p3, t3);
        float ew = fmaxf(ex1 - ex0, 0.0f), eh = fmaxf(ey1 - ey0, 0.0f);
        float enc = ew * eh;
        float giou = iou - (enc - uni) / enc;
        s_giou = (double)(1.0f - giou);
    }

    // deterministic fixed-order wave butterfly sum (same result every replay)
    double vals[4] = { s_wnll, s_w, s_l1, s_giou };
    #pragma unroll
    for (int k = 0; k < 4; ++k) {
        double v = vals[k];
        #pragma unroll
        for (int off = 32; off > 0; off >>= 1) v += __shfl_xor(v, off);
        if (tid == 0) partials[b * 4 + k] = v;
    }

    // ---- last-block-done finalize (device-scope fence + atomic) ----
    if (do_finalize && tid == 0) {
        __threadfence();                         // partials visible device-wide
        unsigned prev = atomicAdd(counter, 1u);  // device-scope by default
        if (prev == Bn - 1) {
            __threadfence();                     // acquire all blocks' partials
            double wnll = 0.0, w = 0.0, l1s = 0.0, gis = 0.0;
            for (int bb = 0; bb < Bn; ++bb) {    // fixed order => deterministic
                wnll += partials[bb * 4 + 0];
                w    += partials[bb * 4 + 1];
                l1s  += partials[bb * 4 + 2];
                gis  += partials[bb * 4 + 3];
            }
            double nb = (double)(Bn * Tn);
            out[0] = (float)(wnll / w + BBOX_SCALE_D * (l1s / nb) +
                             GIOU_SCALE_D * (gis / nb));
        }
    }
}

// ---------------------------------------------------------------------------
// Fallback finalize (only used when ws has no room for gcost/counter path)
// ---------------------------------------------------------------------------
__global__ void finalize_kernel(const double* __restrict__ partials,
                                float* __restrict__ out)
{
    if (threadIdx.x != 0 || blockIdx.x != 0) return;
    double wnll = 0.0, w = 0.0, l1 = 0.0, gi = 0.0;
    for (int b = 0; b < Bn; ++b) {
        wnll += partials[b * 4 + 0];
        w    += partials[b * 4 + 1];
        l1   += partials[b * 4 + 2];
        gi   += partials[b * 4 + 3];
    }
    double nb = (double)(Bn * Tn);
    double loss = wnll / w + BBOX_SCALE_D * (l1 / nb) + GIOU_SCALE_D * (gi / nb);
    out[0] = (float)loss;
}

// ---------------------------------------------------------------------------
extern "C" void kernel_launch(void* const* d_in, const int* in_sizes, int n_in,
                              void* d_out, int out_size, void* d_ws, size_t ws_size,
                              hipStream_t stream)
{
    const float* logits        = (const float*)d_in[0];
    const float* pred_bbox     = (const float*)d_in[1];
    const float* target_bbox   = (const float*)d_in[2];
    const int*   target_labels = (const int*)d_in[3];
    float* out = (float*)d_out;

    char* ws = (char*)d_ws;
    unsigned* counter = (unsigned*)(ws + 4096);            // 4 B
    double* partials  = (double*)(ws + 8448);              // 1024 B
    float* gcost      = (float*)(ws + 16384);              // 2457600 B (optional)

    const size_t cost_bytes = (size_t)Bn * Nrows * Mcols * sizeof(float);
    const int use_gcost = (ws_size >= 16384 + cost_bytes) ? 1 : 0;

    if (use_gcost) {
        const int total = Bn * Nrows * Mcols;
        hipLaunchKernelGGL(cost_kernel, dim3((total + 255) / 256), dim3(256), 0, stream,
                           logits, pred_bbox, target_bbox, target_labels, gcost, counter);
    }
    hipLaunchKernelGGL(lsa_kernel, dim3(Bn), dim3(64), 0, stream,
                       logits, pred_bbox, target_bbox, target_labels,
                       gcost, use_gcost, partials, counter,
                       /*do_finalize=*/use_gcost, out);
    if (!use_gcost) {
        hipLaunchKernelGGL(finalize_kernel, dim3(1), dim3(1), 0, stream, partials, out);
    }
}